// Round 5
// baseline (287.126 us; speedup 1.0000x reference)
//
#include <hip/hip_runtime.h>
#include <stdint.h>

// ---------------------------------------------------------------------------
// TSA block: out = x + softmax((h Wq)(h Wk)^T / 32) (h Wv),  h = x + pos_enc
// B=4, S=2048, D=1024. fp32 I/O, f16 MFMA internals.
// R11: R10 geometry kept bit-identical (128x128, 4 waves, same staging bytes,
//      fragment addressing, epilogues, grids 1536/1024/512). K-loop phase
//      interior restructured for in-wave LDS||MFMA overlap:
//      - frags for slice s are ds_read in phase s-1 (named reg sets A/B,
//        loop unrolled x2); phase s = [read frags(s+1)->NEXT | stage(s+4)]
//        -> sched_barrier -> MFMA(CUR). Compiler auto-emits lgkmcnt(8):
//        the 8 new reads stay in flight UNDER the MFMA cluster.
//      - 5 LDS regions (80KB, still 2 blk/CU = 160KB exactly): stage(s+4)
//        targets region (s-1)%5 whose reads completed in phase s-2 (two
//        barriers of margin); end-of-phase vmcnt(8) ensures unit s+2
//        resident for next phase's frag-read (tail 4->0).
//      - ONE barrier per phase (was 2): ledger margins allow it.
// R10 post-mortem: reads->barrier->lgkm(0)->MFMA serialized the per-CU
// LDS burst (~585cy) with the MFMA burst (~620cy) in lockstep -> 28% util.
// Facts carried: [rows][32]-f16 LDS layout + linear gload_lds staging is
// counter-verified conflict-free; QKV not memory-bound; max |logit| ~ 8 =>
// exp fits f16; K-slice order unchanged => results bit-identical to R10.
// ---------------------------------------------------------------------------

#define AS1(p) ((__attribute__((address_space(1))) void*)(p))
#define AS3(p) ((__attribute__((address_space(3))) void*)(p))

typedef _Float16 f16x8 __attribute__((ext_vector_type(8)));
typedef _Float16 f16x4 __attribute__((ext_vector_type(4)));
typedef float f32x4 __attribute__((ext_vector_type(4)));

// ---------------- prep: h = x + pe (f16), Wt = W^T (f16), rowsum = 0 -------
__global__ __launch_bounds__(256) void prep(const float* __restrict__ x,
                                            _Float16* __restrict__ h,
                                            const float* __restrict__ Wq,
                                            const float* __restrict__ Wk,
                                            const float* __restrict__ Wv,
                                            _Float16* __restrict__ Wt,
                                            float* __restrict__ rowsum) {
  const int bx = blockIdx.x;
  const int tid = threadIdx.x;
  if (bx < 8192) {
    // make_h: 4 consecutive d per thread
    const size_t e = ((size_t)bx * 256 + tid) * 4;
    const int d = (int)(e & 1023);
    const int s = (int)((e >> 10) & 2047);
    const float4 xv = *(const float4*)(x + e);
    const int half = d >> 9;
    const int j0 = d & 511;
    const float c = -0.017988946039016f;  // -ln(10000)/512
    f16x4 o;
#pragma unroll
    for (int t = 0; t < 4; t++) {
      const float r = __expf((float)(j0 + t) * c);
      const float a = (float)s * r;
      const float p = half ? __cosf(a) : __sinf(a);
      const float xe = (t == 0) ? xv.x : (t == 1) ? xv.y : (t == 2) ? xv.z : xv.w;
      o[t] = (_Float16)(xe + p);
    }
    *(f16x4*)(h + e) = o;
  } else if (bx < 11264) {
    // transpose_w: 32x32 tile
    __shared__ float t[32][33];
    const int w = bx - 8192;              // [0, 3072)
    const int z = w >> 10;
    const int rem = w & 1023;
    const int n0 = (rem & 31) * 32, k0 = (rem >> 5) * 32;
    const float* W = (z == 0) ? Wq : (z == 1) ? Wk : Wv;
    _Float16* o = Wt + (size_t)z * 1048576;
    const int tx = tid & 31, ty = tid >> 5;
#pragma unroll
    for (int i = ty; i < 32; i += 8)
      t[i][tx] = W[(size_t)(k0 + i) * 1024 + (n0 + tx)];
    __syncthreads();
#pragma unroll
    for (int i = ty; i < 32; i += 8)
      o[(size_t)(n0 + i) * 1024 + (k0 + tx)] = (_Float16)t[tx][i];
  } else {
    // zero rowsum[8192]
    rowsum[(bx - 11264) * 256 + tid] = 0.f;
  }
}

// frag-read and MFMA-cluster macros (expand in-kernel; constant reg indices)
#define READ_FRAGS(r, AF, BF)                                                 \
  {                                                                           \
    const int rb_ = (r) * 4096;                                               \
    _Pragma("unroll") for (int i_ = 0; i_ < 4; i_++)                          \
      AF[i_] = *(const f16x8*)&As[rb_ + (wr * 64 + i_ * 16 + l16) * 32 + quad * 8]; \
    _Pragma("unroll") for (int j_ = 0; j_ < 4; j_++)                          \
      BF[j_] = *(const f16x8*)&Bs[rb_ + (wc * 64 + j_ * 16 + l16) * 32 + quad * 8]; \
  }

#define DO_MFMA(AF, BF)                                                       \
  {                                                                           \
    __builtin_amdgcn_s_setprio(1);                                            \
    _Pragma("unroll") for (int i_ = 0; i_ < 4; i_++)                          \
      _Pragma("unroll") for (int j_ = 0; j_ < 4; j_++)                        \
        acc[i_][j_] = __builtin_amdgcn_mfma_f32_16x16x32_f16(AF[i_], BF[j_],  \
                                                             acc[i_][j_], 0, 0, 0); \
    __builtin_amdgcn_s_setprio(0);                                            \
  }

#define END_PHASE(sv)                                                         \
  {                                                                           \
    if ((sv) + 1 < NS) {                                                      \
      if ((sv) + 5 <= NS)      asm volatile("s_waitcnt vmcnt(8)" ::: "memory"); \
      else if ((sv) + 4 == NS) asm volatile("s_waitcnt vmcnt(4)" ::: "memory"); \
      else                     asm volatile("s_waitcnt vmcnt(0)" ::: "memory"); \
      __builtin_amdgcn_s_barrier();                                           \
    }                                                                         \
  }

// ---------------- 128x128 A·B^T GEMM, reg-dbuf fine-phase pipeline ---------
// A: [M x K] row-major f16, Bt: [N x K] row-major f16 (i.e. B^T).
// FLAT grid with XCD-aware decode (XCD ~ bid%8; same-A blocks -> same XCD).
// MODE 0 (QKV): grid 1536. q,k: C f16 row-major = A·B + bias(z).
//   z=2 (v): writes vT[b][d][s] = (A·B + bv)[s][d] directly (f16x4).
// MODE 1 (exp-logits^T): grid 1024.
//   C0[z*sC + n*ldc + m] = exp((A·B)[m][n]/32) f16x4, rowsum atomics.
// MODE 2 (PV^T norm + res): grid 512.
//   C0[z*sC + n*ldc + m] = (A·B)[m][n]/rowsum[n] + X, float4.
template <int MODE>
__global__ __launch_bounds__(256) void gemm_bt(
    const _Float16* __restrict__ A0, long long sA,
    const _Float16* __restrict__ B0, long long sB,
    void* __restrict__ C0, long long sC,
    const float* __restrict__ aux0, const float* __restrict__ aux1,
    const float* __restrict__ aux2, float* __restrict__ rowsum,
    _Float16* __restrict__ vT,
    long long sX, const int K, const int N, const int ldc) {
  __shared__ __align__(16) _Float16 As[5 * 4096];  // 5 regions x [128r x 32k]
  __shared__ __align__(16) _Float16 Bs[5 * 4096];
  const int tid = threadIdx.x;
  const int bid = blockIdx.x;

  int z, bm0, bn0;
  if (MODE == 0) {
    // bid = c + 8*(mhi + 8*(n + 8*z)); m = 8*mhi + c
    const int c = bid & 7, t = bid >> 3;
    const int mhi = t & 7, u = t >> 3;
    bm0 = (mhi * 8 + c) * 128;
    bn0 = (u & 7) * 128;
    z = u >> 3;
  } else if (MODE == 1) {
    // zx = z*16 + x (A-tile id); bid = (zx&7) + 8*((zx>>3) + 8*y)
    const int c = bid & 7, t = bid >> 3;
    const int zx = (t & 7) * 8 + c;
    const int y = t >> 3;
    z = zx >> 4; bm0 = (zx & 15) * 128; bn0 = y * 128;
  } else {
    // zx = z*8 + x; bid = (zx&7) + 8*((zx>>3) + 4*y)
    const int c = bid & 7, t = bid >> 3;
    const int zx = (t & 3) * 8 + c;
    const int y = t >> 2;
    z = zx >> 3; bm0 = (zx & 7) * 128; bn0 = y * 128;
  }
  const _Float16* A = A0 + (size_t)z * sA;
  const _Float16* Bt = B0 + (size_t)z * sB;

  // staging pointers: thread t loads 16B from row (t>>2), col chunk (t&3)*8
  const _Float16* a0 = A + (size_t)(bm0 + (tid >> 2)) * K + (tid & 3) * 8;
  const _Float16* a1 = a0 + (size_t)64 * K;
  const _Float16* b0 = Bt + (size_t)(bn0 + (tid >> 2)) * K + (tid & 3) * 8;
  const _Float16* b1 = b0 + (size_t)64 * K;

  // one stage-unit = 4 gload_lds: slice kt -> region r (linear dest, same
  // byte pattern as the verified R8/R10 layout)
  auto stage = [&](int kt, int r) {
    const int k = kt * 32;
    __builtin_amdgcn_global_load_lds(AS1(a0 + k), AS3(&As[r * 4096 + tid * 8]), 16, 0, 0);
    __builtin_amdgcn_global_load_lds(AS1(a1 + k), AS3(&As[r * 4096 + tid * 8 + 2048]), 16, 0, 0);
    __builtin_amdgcn_global_load_lds(AS1(b0 + k), AS3(&Bs[r * 4096 + tid * 8]), 16, 0, 0);
    __builtin_amdgcn_global_load_lds(AS1(b1 + k), AS3(&Bs[r * 4096 + tid * 8 + 2048]), 16, 0, 0);
  };

  const int lane = tid & 63, wave = tid >> 6;
  const int wr = wave >> 1, wc = wave & 1;   // wave -> 64x64 quadrant
  const int quad = lane >> 4, l16 = lane & 15;

  f32x4 acc[4][4];
#pragma unroll
  for (int i = 0; i < 4; i++)
#pragma unroll
    for (int j = 0; j < 4; j++) {
      f32x4 zz = {0.f, 0.f, 0.f, 0.f};
      acc[i][j] = zz;
    }

  const int NS = K >> 5;  // 32-k slices; NS in {32, 64} here (even, >= 5)

  // prologue: stage units 0..3 into regions 0..3; wait units 0,1; read frags 0
  stage(0, 0); stage(1, 1); stage(2, 2); stage(3, 3);
  asm volatile("s_waitcnt vmcnt(8)" ::: "memory");
  __builtin_amdgcn_s_barrier();

  f16x8 afA[4], bfA[4], afB[4], bfB[4];
  READ_FRAGS(0, afA, bfA);

  int rr = 1;  // region of next frag-read (slice s+1)
  int sr = 4;  // region of next stage (unit s+4)

  for (int s = 0; s < NS; s += 2) {
    // ---- phase s: compute setA (slice s), prefetch slice s+1 into setB
    if (s + 1 < NS) { READ_FRAGS(rr, afB, bfB); rr = (rr == 4) ? 0 : rr + 1; }
    if (s + 4 < NS) { stage(s + 4, sr); sr = (sr == 4) ? 0 : sr + 1; }
    __builtin_amdgcn_sched_barrier(0);  // pin reads/stage above MFMA cluster
    DO_MFMA(afA, bfA);                  // auto-wait: lgkmcnt(8) (setB in flight)
    __builtin_amdgcn_sched_barrier(0);
    END_PHASE(s);

    // ---- phase s+1: compute setB (slice s+1), prefetch slice s+2 into setA
    const int s1 = s + 1;
    if (s1 < NS) {
      if (s1 + 1 < NS) { READ_FRAGS(rr, afA, bfA); rr = (rr == 4) ? 0 : rr + 1; }
      if (s1 + 4 < NS) { stage(s1 + 4, sr); sr = (sr == 4) ? 0 : sr + 1; }
      __builtin_amdgcn_sched_barrier(0);
      DO_MFMA(afB, bfB);
      __builtin_amdgcn_sched_barrier(0);
      END_PHASE(s1);
    }
  }

  // epilogue: C/D layout col = lane&15 (in colb), row = quad*4 + reg
  const int rowb = bm0 + wr * 64 + quad * 4;
  const int colb = bn0 + wc * 64 + l16;
  if (MODE == 0) {
    const float* bias = (z == 0) ? aux0 : (z == 1) ? aux1 : aux2;
    if (z == 2) {
      // v: write vT[b][d][s] directly; rows rowb+i*16..+3 are 4 consecutive s
      const int b = rowb >> 11, sl = rowb & 2047;
      _Float16* vb = vT + (size_t)b * 2097152;
#pragma unroll
      for (int i = 0; i < 4; i++)
#pragma unroll
        for (int j = 0; j < 4; j++) {
          const int gn = colb + j * 16;
          const float bb = bias[gn];
          f16x4 o;
#pragma unroll
          for (int r = 0; r < 4; r++) o[r] = (_Float16)(acc[i][j][r] + bb);
          *(f16x4*)&vb[(size_t)gn * 2048 + sl + i * 16] = o;
        }
    } else {
      _Float16* C = (_Float16*)C0 + (size_t)z * sC;
#pragma unroll
      for (int i = 0; i < 4; i++)
#pragma unroll
        for (int j = 0; j < 4; j++) {
          const int gn = colb + j * 16;
          const float bb = bias[gn];
#pragma unroll
          for (int r = 0; r < 4; r++)
            C[(size_t)(rowb + i * 16 + r) * N + gn] = (_Float16)(acc[i][j][r] + bb);
        }
    }
  } else if (MODE == 1) {
    // store exp(l)[n][m..m+3] f16x4; accumulate fp32 rowsum[n] via atomics
    _Float16* C = (_Float16*)C0 + (size_t)z * sC;
    float rs[4] = {0.f, 0.f, 0.f, 0.f};
#pragma unroll
    for (int i = 0; i < 4; i++)
#pragma unroll
      for (int j = 0; j < 4; j++) {
        const int gn = colb + j * 16;
        f16x4 o;
        float pj = 0.f;
#pragma unroll
        for (int r = 0; r < 4; r++) {
          const float e = __expf(acc[i][j][r] * 0.03125f);
          o[r] = (_Float16)e;
          pj += e;
        }
        rs[j] += pj;
        *(f16x4*)&C[(size_t)gn * ldc + rowb + i * 16] = o;
      }
#pragma unroll
    for (int j = 0; j < 4; j++) {
      float v = rs[j];
      v += __shfl_xor(v, 16);
      v += __shfl_xor(v, 32);
      if (quad == 0) atomicAdd(&rowsum[z * 2048 + colb + j * 16], v);
    }
  } else {
    // C'[m=d][n=s] = acc/rowsum[s] + X; float4 store + float4 residual read
    float* C = (float*)C0 + (size_t)z * sC;
    const float* X = aux0 + (size_t)z * sX;
    float inv[4];
#pragma unroll
    for (int j = 0; j < 4; j++)
      inv[j] = 1.0f / rowsum[z * 2048 + colb + j * 16];
#pragma unroll
    for (int i = 0; i < 4; i++)
#pragma unroll
      for (int j = 0; j < 4; j++) {
        const int gn = colb + j * 16;
        const size_t base = (size_t)gn * ldc + rowb + i * 16;
        const float4 xv = *(const float4*)(X + base);
        float4 o;
        o.x = acc[i][j][0] * inv[j] + xv.x;
        o.y = acc[i][j][1] * inv[j] + xv.y;
        o.z = acc[i][j][2] * inv[j] + xv.z;
        o.w = acc[i][j][3] * inv[j] + xv.w;
        *(float4*)(C + base) = o;
      }
  }
}

// ---------------------------------------------------------------------------
extern "C" void kernel_launch(void* const* d_in, const int* in_sizes, int n_in,
                              void* d_out, int out_size, void* d_ws, size_t ws_size,
                              hipStream_t stream) {
  (void)in_sizes; (void)n_in; (void)out_size; (void)ws_size;
  const float* x  = (const float*)d_in[0];
  const float* Wq = (const float*)d_in[1];
  const float* bq = (const float*)d_in[2];
  const float* Wk = (const float*)d_in[3];
  const float* bk = (const float*)d_in[4];
  const float* Wv = (const float*)d_in[5];
  const float* bv = (const float*)d_in[6];
  float* out = (float*)d_out;
  char* ws = (char*)d_ws;

  // workspace layout (bytes):
  //   [0, 16M)        h (f16)          -- dead after QKV
  //   [16M, 22M)      Wt (f16 x3)      -- dead after QKV
  //   [22M, 70M)      qkv: q, k row-major; third slot holds vT[b][d][s]
  //   [70M, 102M)     attn_unnorm = exp(logits) (f16)
  //   [102M, +32K)    rowsum (fp32[8192]), zeroed by prep
  _Float16* h    = (_Float16*)(ws);
  _Float16* Wt   = (_Float16*)(ws + 16777216);
  _Float16* qkv  = (_Float16*)(ws + 23068672);
  _Float16* attn = (_Float16*)(ws + 73400320);      // exp(logits), unnormalized
  float* rowsum  = (float*)   (ws + 106954752);

  const long long E = 8388608;  // elements per [8192 x 1024] f16 tensor
  _Float16* vT = qkv + 2 * E;   // [4][1024][2048], written directly by MODE 0

  // prep: [0,8192) make h; [8192,11264) transpose W; [11264,11296) zero rowsum
  prep<<<11296, 256, 0, stream>>>(x, h, Wq, Wk, Wv, Wt, rowsum);

  // QKV: [8192x1024] @ Wt_z -> q,k row-major f16 + bias; v written as vT
  gemm_bt<0><<<1536, 256, 0, stream>>>(
      h, 0LL, Wt, 1048576LL, qkv, E, bq, bk, bv, nullptr, vT,
      0LL, 1024, 1024, 0);

  // exp-logits^T (A=k, Bt=q -> attn[b][q][k] = exp(l/32), rowsum atomics)
  gemm_bt<1><<<1024, 256, 0, stream>>>(
      qkv + E, 2097152LL, qkv, 2097152LL, attn, 4194304LL,
      nullptr, nullptr, nullptr, rowsum, nullptr,
      0LL, 1024, 2048, 2048);

  // PV^T: A=vT_b, Bt=attn_b -> out[b][s][d] = (P~V)[s][d]/rowsum[s] + x
  gemm_bt<2><<<512, 256, 0, stream>>>(
      vT, 2097152LL, attn, 4194304LL, out, 2097152LL,
      x, nullptr, nullptr, rowsum, nullptr,
      2097152LL, 2048, 2048, 1024);
}

// Round 6
// 265.148 us; speedup vs baseline: 1.0829x; 1.0829x over previous
//
#include <hip/hip_runtime.h>
#include <stdint.h>

// ---------------------------------------------------------------------------
// TSA block: out = x + softmax((h Wq)(h Wk)^T / 32) (h Wv),  h = x + pos_enc
// B=4, S=2048, D=1024. fp32 I/O, f16 MFMA internals.
// R12: MODE0/MODE1 on a faithful m201-style quadrant-phase schedule
//      (gemm256): 256x256 tile, 8 waves (2M x 4N, 128x64 each), BK=64,
//      LDS [buf2][kk2][256r][32k] x (A,B) = 128KB, 1 blk/CU.
//      Per K-tile T, 4 phases = output quadrants (mq,nq): reads P0:A0(8)+
//      B0(4) / P1:A1(8) / P2:B1(4) / P3:none — A/B reg-sets REUSED across
//      phases (the piece R9-R11 missed: ds_read count per MFMA halves).
//      Stages (2 gload-instr/phase): P0:(T+1).Bh0, P1:(T+1).Bh1,
//      P2:(T+2).Ah0, P3:(T+2).Ah1 — each target's last read is >=1 drained
//      phase earlier (ledger proven). vmcnt(4) ONCE per K-tile at P3
//      (2 newest half-stages in flight), tail 0; prologue K0*+K1.A,vmcnt(4).
//      Phase = {reads|stage, bar, lgkm(0)+schedbar, prio1, 16 MFMA, prio0,
//      bar} exactly per the verified template. MODE2 keeps R10's proven
//      fine-phase 128^2 core (gemm_pv); prep unchanged.
// Facts carried: [r][32k] layout conflict-free (counters: conflicts==DMA
// signature R6-R11); R11 lesson: runtime-rotating region indices cost 25%
// VALUBusy -> all indices here are compile-time per phase; max|logit|~8.
// ---------------------------------------------------------------------------

#define AS1(p) ((__attribute__((address_space(1))) void*)(p))
#define AS3(p) ((__attribute__((address_space(3))) void*)(p))

typedef _Float16 f16x8 __attribute__((ext_vector_type(8)));
typedef _Float16 f16x4 __attribute__((ext_vector_type(4)));
typedef float f32x4 __attribute__((ext_vector_type(4)));

// ---------------- prep: h = x + pe (f16), Wt = W^T (f16), rowsum = 0 -------
__global__ __launch_bounds__(256) void prep(const float* __restrict__ x,
                                            _Float16* __restrict__ h,
                                            const float* __restrict__ Wq,
                                            const float* __restrict__ Wk,
                                            const float* __restrict__ Wv,
                                            _Float16* __restrict__ Wt,
                                            float* __restrict__ rowsum) {
  const int bx = blockIdx.x;
  const int tid = threadIdx.x;
  if (bx < 8192) {
    const size_t e = ((size_t)bx * 256 + tid) * 4;
    const int d = (int)(e & 1023);
    const int s = (int)((e >> 10) & 2047);
    const float4 xv = *(const float4*)(x + e);
    const int half = d >> 9;
    const int j0 = d & 511;
    const float c = -0.017988946039016f;  // -ln(10000)/512
    f16x4 o;
#pragma unroll
    for (int t = 0; t < 4; t++) {
      const float r = __expf((float)(j0 + t) * c);
      const float a = (float)s * r;
      const float p = half ? __cosf(a) : __sinf(a);
      const float xe = (t == 0) ? xv.x : (t == 1) ? xv.y : (t == 2) ? xv.z : xv.w;
      o[t] = (_Float16)(xe + p);
    }
    *(f16x4*)(h + e) = o;
  } else if (bx < 11264) {
    __shared__ float t[32][33];
    const int w = bx - 8192;
    const int z = w >> 10;
    const int rem = w & 1023;
    const int n0 = (rem & 31) * 32, k0 = (rem >> 5) * 32;
    const float* W = (z == 0) ? Wq : (z == 1) ? Wk : Wv;
    _Float16* o = Wt + (size_t)z * 1048576;
    const int tx = tid & 31, ty = tid >> 5;
#pragma unroll
    for (int i = ty; i < 32; i += 8)
      t[i][tx] = W[(size_t)(k0 + i) * 1024 + (n0 + tx)];
    __syncthreads();
#pragma unroll
    for (int i = ty; i < 32; i += 8)
      o[(size_t)(n0 + i) * 1024 + (k0 + tx)] = (_Float16)t[tx][i];
  } else {
    rowsum[(bx - 11264) * 256 + tid] = 0.f;
  }
}

// ---- gemm256 macros (expand in kernel scope; all indices compile-time) ----
#define RD_A(SET, S_)                                                         \
  {                                                                           \
    _Pragma("unroll") for (int fi = 0; fi < 4; fi++)                          \
      _Pragma("unroll") for (int kk = 0; kk < 2; kk++)                        \
        SET[fi * 2 + kk] = *(const f16x8*)&As[bb][kk][                        \
            (wr * 128 + (S_) * 64 + fi * 16 + l16) * 32 + quad * 8];          \
  }
#define RD_B(SET, S_)                                                         \
  {                                                                           \
    _Pragma("unroll") for (int fj = 0; fj < 2; fj++)                          \
      _Pragma("unroll") for (int kk = 0; kk < 2; kk++)                        \
        SET[fj * 2 + kk] = *(const f16x8*)&Bs[bb][kk][                        \
            (wc * 64 + (S_) * 32 + fj * 16 + l16) * 32 + quad * 8];           \
  }
#define MFMA16(ASET, BSET, MQ, NQ)                                            \
  {                                                                           \
    __builtin_amdgcn_s_setprio(1);                                            \
    _Pragma("unroll") for (int fi = 0; fi < 4; fi++)                          \
      _Pragma("unroll") for (int fj = 0; fj < 2; fj++)                        \
        _Pragma("unroll") for (int kk = 0; kk < 2; kk++)                      \
          acc[(MQ) * 4 + fi][(NQ) * 2 + fj] =                                 \
              __builtin_amdgcn_mfma_f32_16x16x32_f16(                         \
                  ASET[fi * 2 + kk], BSET[fj * 2 + kk],                       \
                  acc[(MQ) * 4 + fi][(NQ) * 2 + fj], 0, 0, 0);                \
    __builtin_amdgcn_s_setprio(0);                                            \
  }
#define PHASE_WAIT()                                                          \
  __builtin_amdgcn_s_barrier();                                               \
  asm volatile("s_waitcnt lgkmcnt(0)" ::: "memory");                          \
  __builtin_amdgcn_sched_barrier(0);

// ---------------- 256x256 A·B^T GEMM, m201 quadrant-phase schedule ---------
// A: [M x K] row-major f16, Bt: [N x K] row-major f16 (i.e. B^T).
// MODE 0 (QKV): grid 384 (32m x {3z x 4n}). q,k: C f16 row-major + bias(z);
//   z=2: vT[b][d][s] direct (f16x4).
// MODE 1 (exp-logits^T): grid 256 (4z x 8m x 8n).
//   C0[z*sC + n*ldc + m] = exp((A·B)[m][n]/32) f16x4, rowsum atomics.
template <int MODE>
__global__ __launch_bounds__(512) void gemm256(
    const _Float16* __restrict__ A0, long long sA,
    const _Float16* __restrict__ B0, long long sB,
    void* __restrict__ C0, long long sC,
    const float* __restrict__ aux0, const float* __restrict__ aux1,
    const float* __restrict__ aux2, float* __restrict__ rowsum,
    _Float16* __restrict__ vT, const int K, const int N, const int ldc) {
  __shared__ __align__(16) _Float16 As[2][2][8192];  // [buf][kk][256r x 32k]
  __shared__ __align__(16) _Float16 Bs[2][2][8192];
  const int tid = threadIdx.x;
  const int bid = blockIdx.x;

  int z, bm0, bn0;
  if (MODE == 0) {
    const int w = (bid & 7) * 48 + (bid >> 3);   // [0,384), XCD chunk 48
    const int m = w / 12, r = w - m * 12;        // m-major: XCD shares h rows
    z = r >> 2; bn0 = (r & 3) * 256; bm0 = m * 256;
  } else {
    const int w = (bid & 7) * 32 + (bid >> 3);   // [0,256), XCD chunk 32
    z = w >> 6;
    const int r = w & 63;
    bm0 = (r >> 3) * 256; bn0 = (r & 7) * 256;
  }
  const _Float16* A = A0 + (size_t)z * sA;
  const _Float16* Bt = B0 + (size_t)z * sB;

  // staging: thread t -> row (t>>2) within a 128-row half, chunk (t&3)*8.
  // LDS dest linear in tid (verified conflict-free layout, no swizzle).
  const _Float16* aS = A + (size_t)(bm0 + (tid >> 2)) * K + (tid & 3) * 8;
  const _Float16* bS = Bt + (size_t)(bn0 + (tid >> 2)) * K + (tid & 3) * 8;
  const size_t halfStep = (size_t)128 * K;

  auto stageA = [&](int X, int h) {  // A-half h of K-tile X: 2 gload instr
    const int b = X & 1;
    const _Float16* s = aS + (size_t)X * 64 + (size_t)h * halfStep;
    _Float16* d = &As[b][0][h * 4096 + tid * 8];
    __builtin_amdgcn_global_load_lds(AS1(s), AS3(d), 16, 0, 0);
    __builtin_amdgcn_global_load_lds(AS1(s + 32), AS3(d + 8192), 16, 0, 0);
  };
  auto stageB = [&](int X, int h) {
    const int b = X & 1;
    const _Float16* s = bS + (size_t)X * 64 + (size_t)h * halfStep;
    _Float16* d = &Bs[b][0][h * 4096 + tid * 8];
    __builtin_amdgcn_global_load_lds(AS1(s), AS3(d), 16, 0, 0);
    __builtin_amdgcn_global_load_lds(AS1(s + 32), AS3(d + 8192), 16, 0, 0);
  };

  const int lane = tid & 63, wave = tid >> 6;
  const int wr = wave >> 2, wc = wave & 3;   // 2M x 4N waves, 128x64 each
  const int quad = lane >> 4, l16 = lane & 15;

  f32x4 acc[8][4];
#pragma unroll
  for (int i = 0; i < 8; i++)
#pragma unroll
    for (int j = 0; j < 4; j++) {
      f32x4 zz = {0.f, 0.f, 0.f, 0.f};
      acc[i][j] = zz;
    }

  const int nt = K >> 6;  // K-tiles of 64; nt = 16 or 32 here (>= 2)

  // prologue: K0 all 4 halves + K1.A halves (12 instr); K0 resident ->
  // allow newest 4 (K1.A0,A1) outstanding = steady-entry invariant.
  stageA(0, 0); stageA(0, 1); stageB(0, 0); stageB(0, 1);
  stageA(1, 0); stageA(1, 1);
  asm volatile("s_waitcnt vmcnt(4)" ::: "memory");
  __builtin_amdgcn_s_barrier();

  f16x8 a0[8], a1[8], b0f[4], b1f[4];

  for (int T = 0; T < nt; ++T) {
    const int bb = T & 1;
    // ---- P0: quadrant (mq0, nq0)
    RD_A(a0, 0);
    RD_B(b0f, 0);
    if (T + 1 < nt) stageB(T + 1, 0);     // (T+1).Bh0: buf^1, reads drained
    PHASE_WAIT();
    MFMA16(a0, b0f, 0, 0);
    __builtin_amdgcn_s_barrier();
    // ---- P1: quadrant (mq1, nq0)
    RD_A(a1, 1);
    if (T + 1 < nt) stageB(T + 1, 1);     // (T+1).Bh1
    PHASE_WAIT();
    MFMA16(a1, b0f, 1, 0);
    __builtin_amdgcn_s_barrier();
    // ---- P2: quadrant (mq0, nq1) — reuses a0 regs
    RD_B(b1f, 1);
    if (T + 2 < nt) stageA(T + 2, 0);     // (T+2).Ah0: A reads done at P1
    PHASE_WAIT();
    MFMA16(a0, b1f, 0, 1);
    __builtin_amdgcn_s_barrier();
    // ---- P3: quadrant (mq1, nq1) — reuses a1, b1f regs; no ds_reads
    if (T + 2 < nt) stageA(T + 2, 1);     // (T+2).Ah1
    PHASE_WAIT();
    MFMA16(a1, b1f, 1, 1);
    // ---- K-tile boundary: the ONLY vmcnt (counted, never drains mid-loop)
    if (T + 1 < nt) {
      if (T + 2 < nt) asm volatile("s_waitcnt vmcnt(4)" ::: "memory");
      else            asm volatile("s_waitcnt vmcnt(0)" ::: "memory");
      __builtin_amdgcn_s_barrier();
    }
  }

  // epilogue: C/D layout col = lane&15 (in colb), row = quad*4 + reg
  const int rowb = bm0 + wr * 128 + quad * 4;
  const int colb = bn0 + wc * 64 + l16;
  if (MODE == 0) {
    const float* bias = (z == 0) ? aux0 : (z == 1) ? aux1 : aux2;
    if (z == 2) {
      const int b_ = rowb >> 11, sl = rowb & 2047;
      _Float16* vb = vT + (size_t)b_ * 2097152;
#pragma unroll
      for (int i = 0; i < 8; i++)
#pragma unroll
        for (int j = 0; j < 4; j++) {
          const int gn = colb + j * 16;
          const float bb2 = bias[gn];
          f16x4 o;
#pragma unroll
          for (int r = 0; r < 4; r++) o[r] = (_Float16)(acc[i][j][r] + bb2);
          *(f16x4*)&vb[(size_t)gn * 2048 + sl + i * 16] = o;
        }
    } else {
      _Float16* C = (_Float16*)C0 + (size_t)z * sC;
#pragma unroll
      for (int i = 0; i < 8; i++)
#pragma unroll
        for (int j = 0; j < 4; j++) {
          const int gn = colb + j * 16;
          const float bb2 = bias[gn];
#pragma unroll
          for (int r = 0; r < 4; r++)
            C[(size_t)(rowb + i * 16 + r) * N + gn] = (_Float16)(acc[i][j][r] + bb2);
        }
    }
  } else {
    _Float16* C = (_Float16*)C0 + (size_t)z * sC;
    float rs[4] = {0.f, 0.f, 0.f, 0.f};
#pragma unroll
    for (int i = 0; i < 8; i++)
#pragma unroll
      for (int j = 0; j < 4; j++) {
        const int gn = colb + j * 16;
        f16x4 o;
        float pj = 0.f;
#pragma unroll
        for (int r = 0; r < 4; r++) {
          const float e = __expf(acc[i][j][r] * 0.03125f);
          o[r] = (_Float16)e;
          pj += e;
        }
        rs[j] += pj;
        *(f16x4*)&C[(size_t)gn * ldc + rowb + i * 16] = o;
      }
#pragma unroll
    for (int j = 0; j < 4; j++) {
      float v = rs[j];
      v += __shfl_xor(v, 16);
      v += __shfl_xor(v, 32);
      if (quad == 0) atomicAdd(&rowsum[z * 2048 + colb + j * 16], v);
    }
  }
}

// ---------------- PV^T: R10's proven fine-phase 128^2 core -----------------
__global__ __launch_bounds__(256) void gemm_pv(
    const _Float16* __restrict__ A0, long long sA,
    const _Float16* __restrict__ B0, long long sB,
    float* __restrict__ C0, long long sC,
    const float* __restrict__ X0, const float* __restrict__ rowsum,
    long long sX, const int K, const int ldc) {
  __shared__ __align__(16) _Float16 As[4 * 4096];
  __shared__ __align__(16) _Float16 Bs[4 * 4096];
  const int tid = threadIdx.x;
  const int bid = blockIdx.x;

  const int c = bid & 7, t0 = bid >> 3;
  const int zx = (t0 & 3) * 8 + c;
  const int y = t0 >> 2;
  const int z = zx >> 3;
  const int bm0 = (zx & 7) * 128, bn0 = y * 128;

  const _Float16* A = A0 + (size_t)z * sA;
  const _Float16* Bt = B0 + (size_t)z * sB;

  const _Float16* a0 = A + (size_t)(bm0 + (tid >> 2)) * K + (tid & 3) * 8;
  const _Float16* a1 = a0 + (size_t)64 * K;
  const _Float16* b0 = Bt + (size_t)(bn0 + (tid >> 2)) * K + (tid & 3) * 8;
  const _Float16* b1 = b0 + (size_t)64 * K;

  auto stage = [&](int s) {
    const int r = s & 3;
    const int k = s * 32;
    __builtin_amdgcn_global_load_lds(AS1(a0 + k), AS3(&As[r * 4096 + tid * 8]), 16, 0, 0);
    __builtin_amdgcn_global_load_lds(AS1(a1 + k), AS3(&As[r * 4096 + tid * 8 + 2048]), 16, 0, 0);
    __builtin_amdgcn_global_load_lds(AS1(b0 + k), AS3(&Bs[r * 4096 + tid * 8]), 16, 0, 0);
    __builtin_amdgcn_global_load_lds(AS1(b1 + k), AS3(&Bs[r * 4096 + tid * 8 + 2048]), 16, 0, 0);
  };

  const int lane = tid & 63, wave = tid >> 6;
  const int wr = wave >> 1, wc = wave & 1;
  const int quad = lane >> 4, l16 = lane & 15;

  f32x4 acc[4][4];
#pragma unroll
  for (int i = 0; i < 4; i++)
#pragma unroll
    for (int j = 0; j < 4; j++) {
      f32x4 zz = {0.f, 0.f, 0.f, 0.f};
      acc[i][j] = zz;
    }

  const int NS = K >> 5;

  stage(0); stage(1); stage(2);
  asm volatile("s_waitcnt vmcnt(8)" ::: "memory");
  __builtin_amdgcn_s_barrier();

  for (int s = 0; s < NS; ++s) {
    const int r = s & 3;
    f16x8 af[4], bf[4];
#pragma unroll
    for (int i = 0; i < 4; i++)
      af[i] = *(const f16x8*)&As[r * 4096 + (wr * 64 + i * 16 + l16) * 32 + quad * 8];
#pragma unroll
    for (int j = 0; j < 4; j++)
      bf[j] = *(const f16x8*)&Bs[r * 4096 + (wc * 64 + j * 16 + l16) * 32 + quad * 8];
    if (s + 3 < NS) stage(s + 3);
    __builtin_amdgcn_s_barrier();
    asm volatile("s_waitcnt lgkmcnt(0)" ::: "memory");
    __builtin_amdgcn_sched_barrier(0);
    __builtin_amdgcn_s_setprio(1);
#pragma unroll
    for (int i = 0; i < 4; i++)
#pragma unroll
      for (int j = 0; j < 4; j++)
        acc[i][j] = __builtin_amdgcn_mfma_f32_16x16x32_f16(af[i], bf[j],
                                                           acc[i][j], 0, 0, 0);
    __builtin_amdgcn_s_setprio(0);
    __builtin_amdgcn_sched_barrier(0);
    if (s + 1 < NS) {
      if (s + 3 < NS)       asm volatile("s_waitcnt vmcnt(8)" ::: "memory");
      else if (s + 3 == NS) asm volatile("s_waitcnt vmcnt(4)" ::: "memory");
      else                  asm volatile("s_waitcnt vmcnt(0)" ::: "memory");
      __builtin_amdgcn_s_barrier();
    }
  }

  const int rowb = bm0 + wr * 64 + quad * 4;
  const int colb = bn0 + wc * 64 + l16;
  float* C = C0 + (size_t)z * sC;
  const float* X = X0 + (size_t)z * sX;
  float inv[4];
#pragma unroll
  for (int j = 0; j < 4; j++)
    inv[j] = 1.0f / rowsum[z * 2048 + colb + j * 16];
#pragma unroll
  for (int i = 0; i < 4; i++)
#pragma unroll
    for (int j = 0; j < 4; j++) {
      const int gn = colb + j * 16;
      const size_t base = (size_t)gn * ldc + rowb + i * 16;
      const float4 xv = *(const float4*)(X + base);
      float4 o;
      o.x = acc[i][j][0] * inv[j] + xv.x;
      o.y = acc[i][j][1] * inv[j] + xv.y;
      o.z = acc[i][j][2] * inv[j] + xv.z;
      o.w = acc[i][j][3] * inv[j] + xv.w;
      *(float4*)(C + base) = o;
    }
}

// ---------------------------------------------------------------------------
extern "C" void kernel_launch(void* const* d_in, const int* in_sizes, int n_in,
                              void* d_out, int out_size, void* d_ws, size_t ws_size,
                              hipStream_t stream) {
  (void)in_sizes; (void)n_in; (void)out_size; (void)ws_size;
  const float* x  = (const float*)d_in[0];
  const float* Wq = (const float*)d_in[1];
  const float* bq = (const float*)d_in[2];
  const float* Wk = (const float*)d_in[3];
  const float* bk = (const float*)d_in[4];
  const float* Wv = (const float*)d_in[5];
  const float* bv = (const float*)d_in[6];
  float* out = (float*)d_out;
  char* ws = (char*)d_ws;

  // workspace layout (bytes):
  //   [0, 16M)        h (f16)          -- dead after QKV
  //   [16M, 22M)      Wt (f16 x3)      -- dead after QKV
  //   [22M, 70M)      qkv: q, k row-major; third slot holds vT[b][d][s]
  //   [70M, 102M)     attn_unnorm = exp(logits) (f16)
  //   [102M, +32K)    rowsum (fp32[8192]), zeroed by prep
  _Float16* h    = (_Float16*)(ws);
  _Float16* Wt   = (_Float16*)(ws + 16777216);
  _Float16* qkv  = (_Float16*)(ws + 23068672);
  _Float16* attn = (_Float16*)(ws + 73400320);
  float* rowsum  = (float*)   (ws + 106954752);

  const long long E = 8388608;  // elements per [8192 x 1024] f16 tensor
  _Float16* vT = qkv + 2 * E;   // [4][1024][2048], written directly by MODE 0

  prep<<<11296, 256, 0, stream>>>(x, h, Wq, Wk, Wv, Wt, rowsum);

  // QKV: [8192x1024] @ Wt_z -> q,k row-major f16 + bias; v written as vT
  gemm256<0><<<384, 512, 0, stream>>>(
      h, 0LL, Wt, 1048576LL, qkv, E, bq, bk, bv, nullptr, vT,
      1024, 1024, 0);

  // exp-logits^T (A=k, Bt=q -> attn[b][q][k] = exp(l/32), rowsum atomics)
  gemm256<1><<<256, 512, 0, stream>>>(
      qkv + E, 2097152LL, qkv, 2097152LL, attn, 4194304LL,
      nullptr, nullptr, nullptr, rowsum, nullptr,
      1024, 2048, 2048);

  // PV^T: A=vT_b, Bt=attn_b -> out[b][s][d] = (P~V)[s][d]/rowsum[s] + x
  gemm_pv<<<512, 256, 0, stream>>>(
      vT, 2097152LL, attn, 4194304LL, out, 2097152LL,
      x, rowsum, 2097152LL, 2048, 1024);
}

// Round 7
// 259.642 us; speedup vs baseline: 1.1059x; 1.0212x over previous
//
#include <hip/hip_runtime.h>
#include <stdint.h>

// ---------------------------------------------------------------------------
// TSA block: out = x + softmax((h Wq)(h Wk)^T / 32) (h Wv),  h = x + pos_enc
// B=4, S=2048, D=1024. fp32 I/O, f16 MFMA internals.
// R13: consolidation of measured-best components per phase (no new structure):
//   - MODE0 QKV: R10 fine-phase 128^2 core, grid 1536 @2blk/CU = 3 exact
//     rounds (measured 73.7us / 28%). R12's 256^2 at grid 384 = 1.5 rounds
//     @1blk/CU lost ~25% to the half-empty tail round (80.6us / 24.7%).
//   - MODE1 exp-logits: R12 gemm256 quadrant-phase 256^2, grid 256 = exactly
//     1 blk/CU, zero tail (measured ~44us / ~32%, best rate this session).
//   - PV: R10 fine-phase 128^2 core, grid 512 @2blk/CU = 1 exact round.
// Session facts: five schedule variants (R8-R12) all land 24-33% MfmaUtil;
// grid/tail shape at low occupancy moves util more than schedule micro-
// structure. [r][32k] LDS layout + linear gload_lds staging counter-verified
// conflict-free. max |logit| ~ 8 => exp fits f16. R11 lesson: runtime-
// rotating indices cost 25% VALUBusy (avoided everywhere).
// ---------------------------------------------------------------------------

#define AS1(p) ((__attribute__((address_space(1))) void*)(p))
#define AS3(p) ((__attribute__((address_space(3))) void*)(p))

typedef _Float16 f16x8 __attribute__((ext_vector_type(8)));
typedef _Float16 f16x4 __attribute__((ext_vector_type(4)));
typedef float f32x4 __attribute__((ext_vector_type(4)));

// ---------------- prep: h = x + pe (f16), Wt = W^T (f16), rowsum = 0 -------
__global__ __launch_bounds__(256) void prep(const float* __restrict__ x,
                                            _Float16* __restrict__ h,
                                            const float* __restrict__ Wq,
                                            const float* __restrict__ Wk,
                                            const float* __restrict__ Wv,
                                            _Float16* __restrict__ Wt,
                                            float* __restrict__ rowsum) {
  const int bx = blockIdx.x;
  const int tid = threadIdx.x;
  if (bx < 8192) {
    const size_t e = ((size_t)bx * 256 + tid) * 4;
    const int d = (int)(e & 1023);
    const int s = (int)((e >> 10) & 2047);
    const float4 xv = *(const float4*)(x + e);
    const int half = d >> 9;
    const int j0 = d & 511;
    const float c = -0.017988946039016f;  // -ln(10000)/512
    f16x4 o;
#pragma unroll
    for (int t = 0; t < 4; t++) {
      const float r = __expf((float)(j0 + t) * c);
      const float a = (float)s * r;
      const float p = half ? __cosf(a) : __sinf(a);
      const float xe = (t == 0) ? xv.x : (t == 1) ? xv.y : (t == 2) ? xv.z : xv.w;
      o[t] = (_Float16)(xe + p);
    }
    *(f16x4*)(h + e) = o;
  } else if (bx < 11264) {
    __shared__ float t[32][33];
    const int w = bx - 8192;
    const int z = w >> 10;
    const int rem = w & 1023;
    const int n0 = (rem & 31) * 32, k0 = (rem >> 5) * 32;
    const float* W = (z == 0) ? Wq : (z == 1) ? Wk : Wv;
    _Float16* o = Wt + (size_t)z * 1048576;
    const int tx = tid & 31, ty = tid >> 5;
#pragma unroll
    for (int i = ty; i < 32; i += 8)
      t[i][tx] = W[(size_t)(k0 + i) * 1024 + (n0 + tx)];
    __syncthreads();
#pragma unroll
    for (int i = ty; i < 32; i += 8)
      o[(size_t)(n0 + i) * 1024 + (k0 + tx)] = (_Float16)t[tx][i];
  } else {
    rowsum[(bx - 11264) * 256 + tid] = 0.f;
  }
}

// ---------------- 128x128 A·B^T GEMM, fine-phase counted-vmcnt pipeline ----
// (R10 core, verbatim — measured 73.7us MODE0, 28% MfmaUtil, 2 blk/CU)
// MODE 0 (QKV): grid 1536. q,k: C f16 row-major = A·B + bias(z);
//   z=2 (v): writes vT[b][d][s] directly (f16x4).
// MODE 2 (PV^T norm + res): grid 512.
//   C0[z*sC + n*ldc + m] = (A·B)[m][n]/rowsum[n] + X, float4.
template <int MODE>
__global__ __launch_bounds__(256) void gemm_bt(
    const _Float16* __restrict__ A0, long long sA,
    const _Float16* __restrict__ B0, long long sB,
    void* __restrict__ C0, long long sC,
    const float* __restrict__ aux0, const float* __restrict__ aux1,
    const float* __restrict__ aux2, float* __restrict__ rowsum,
    _Float16* __restrict__ vT,
    long long sX, const int K, const int N, const int ldc) {
  __shared__ __align__(16) _Float16 As[4 * 4096];  // 4 regions x [128r x 32k]
  __shared__ __align__(16) _Float16 Bs[4 * 4096];
  const int tid = threadIdx.x;
  const int bid = blockIdx.x;

  int z, bm0, bn0;
  if (MODE == 0) {
    const int c = bid & 7, t = bid >> 3;
    const int mhi = t & 7, u = t >> 3;
    bm0 = (mhi * 8 + c) * 128;
    bn0 = (u & 7) * 128;
    z = u >> 3;
  } else {
    const int c = bid & 7, t = bid >> 3;
    const int zx = (t & 3) * 8 + c;
    const int y = t >> 2;
    z = zx >> 3; bm0 = (zx & 7) * 128; bn0 = y * 128;
  }
  const _Float16* A = A0 + (size_t)z * sA;
  const _Float16* Bt = B0 + (size_t)z * sB;

  const _Float16* a0 = A + (size_t)(bm0 + (tid >> 2)) * K + (tid & 3) * 8;
  const _Float16* a1 = a0 + (size_t)64 * K;
  const _Float16* b0 = Bt + (size_t)(bn0 + (tid >> 2)) * K + (tid & 3) * 8;
  const _Float16* b1 = b0 + (size_t)64 * K;

  auto stage = [&](int s) {
    const int r = s & 3;
    const int k = s * 32;
    __builtin_amdgcn_global_load_lds(AS1(a0 + k), AS3(&As[r * 4096 + tid * 8]), 16, 0, 0);
    __builtin_amdgcn_global_load_lds(AS1(a1 + k), AS3(&As[r * 4096 + tid * 8 + 2048]), 16, 0, 0);
    __builtin_amdgcn_global_load_lds(AS1(b0 + k), AS3(&Bs[r * 4096 + tid * 8]), 16, 0, 0);
    __builtin_amdgcn_global_load_lds(AS1(b1 + k), AS3(&Bs[r * 4096 + tid * 8 + 2048]), 16, 0, 0);
  };

  const int lane = tid & 63, wave = tid >> 6;
  const int wr = wave >> 1, wc = wave & 1;
  const int quad = lane >> 4, l16 = lane & 15;

  f32x4 acc[4][4];
#pragma unroll
  for (int i = 0; i < 4; i++)
#pragma unroll
    for (int j = 0; j < 4; j++) {
      f32x4 zz = {0.f, 0.f, 0.f, 0.f};
      acc[i][j] = zz;
    }

  const int NS = K >> 5;

  stage(0); stage(1); stage(2);
  asm volatile("s_waitcnt vmcnt(8)" ::: "memory");
  __builtin_amdgcn_s_barrier();

  for (int s = 0; s < NS; ++s) {
    const int r = s & 3;
    f16x8 af[4], bf[4];
#pragma unroll
    for (int i = 0; i < 4; i++)
      af[i] = *(const f16x8*)&As[r * 4096 + (wr * 64 + i * 16 + l16) * 32 + quad * 8];
#pragma unroll
    for (int j = 0; j < 4; j++)
      bf[j] = *(const f16x8*)&Bs[r * 4096 + (wc * 64 + j * 16 + l16) * 32 + quad * 8];
    if (s + 3 < NS) stage(s + 3);
    __builtin_amdgcn_s_barrier();
    asm volatile("s_waitcnt lgkmcnt(0)" ::: "memory");
    __builtin_amdgcn_sched_barrier(0);
    __builtin_amdgcn_s_setprio(1);
#pragma unroll
    for (int i = 0; i < 4; i++)
#pragma unroll
      for (int j = 0; j < 4; j++)
        acc[i][j] = __builtin_amdgcn_mfma_f32_16x16x32_f16(af[i], bf[j],
                                                           acc[i][j], 0, 0, 0);
    __builtin_amdgcn_s_setprio(0);
    __builtin_amdgcn_sched_barrier(0);
    if (s + 1 < NS) {
      if (s + 3 < NS)       asm volatile("s_waitcnt vmcnt(8)" ::: "memory");
      else if (s + 3 == NS) asm volatile("s_waitcnt vmcnt(4)" ::: "memory");
      else                  asm volatile("s_waitcnt vmcnt(0)" ::: "memory");
      __builtin_amdgcn_s_barrier();
    }
  }

  const int rowb = bm0 + wr * 64 + quad * 4;
  const int colb = bn0 + wc * 64 + l16;
  if (MODE == 0) {
    const float* bias = (z == 0) ? aux0 : (z == 1) ? aux1 : aux2;
    if (z == 2) {
      const int b = rowb >> 11, sl = rowb & 2047;
      _Float16* vb = vT + (size_t)b * 2097152;
#pragma unroll
      for (int i = 0; i < 4; i++)
#pragma unroll
        for (int j = 0; j < 4; j++) {
          const int gn = colb + j * 16;
          const float bb = bias[gn];
          f16x4 o;
#pragma unroll
          for (int r = 0; r < 4; r++) o[r] = (_Float16)(acc[i][j][r] + bb);
          *(f16x4*)&vb[(size_t)gn * 2048 + sl + i * 16] = o;
        }
    } else {
      _Float16* C = (_Float16*)C0 + (size_t)z * sC;
#pragma unroll
      for (int i = 0; i < 4; i++)
#pragma unroll
        for (int j = 0; j < 4; j++) {
          const int gn = colb + j * 16;
          const float bb = bias[gn];
#pragma unroll
          for (int r = 0; r < 4; r++)
            C[(size_t)(rowb + i * 16 + r) * N + gn] = (_Float16)(acc[i][j][r] + bb);
        }
    }
  } else {
    float* C = (float*)C0 + (size_t)z * sC;
    const float* X = aux0 + (size_t)z * sX;
    float inv[4];
#pragma unroll
    for (int j = 0; j < 4; j++)
      inv[j] = 1.0f / rowsum[z * 2048 + colb + j * 16];
#pragma unroll
    for (int i = 0; i < 4; i++)
#pragma unroll
      for (int j = 0; j < 4; j++) {
        const int gn = colb + j * 16;
        const size_t base = (size_t)gn * ldc + rowb + i * 16;
        const float4 xv = *(const float4*)(X + base);
        float4 o;
        o.x = acc[i][j][0] * inv[j] + xv.x;
        o.y = acc[i][j][1] * inv[j] + xv.y;
        o.z = acc[i][j][2] * inv[j] + xv.z;
        o.w = acc[i][j][3] * inv[j] + xv.w;
        *(float4*)(C + base) = o;
      }
  }
}

// ---- gemm256 macros (expand in kernel scope; all indices compile-time) ----
#define RD_A(SET, S_)                                                         \
  {                                                                           \
    _Pragma("unroll") for (int fi = 0; fi < 4; fi++)                          \
      _Pragma("unroll") for (int kk = 0; kk < 2; kk++)                        \
        SET[fi * 2 + kk] = *(const f16x8*)&As[bb][kk][                        \
            (wr * 128 + (S_) * 64 + fi * 16 + l16) * 32 + quad * 8];          \
  }
#define RD_B(SET, S_)                                                         \
  {                                                                           \
    _Pragma("unroll") for (int fj = 0; fj < 2; fj++)                          \
      _Pragma("unroll") for (int kk = 0; kk < 2; kk++)                        \
        SET[fj * 2 + kk] = *(const f16x8*)&Bs[bb][kk][                        \
            (wc * 64 + (S_) * 32 + fj * 16 + l16) * 32 + quad * 8];           \
  }
#define MFMA16(ASET, BSET, MQ, NQ)                                            \
  {                                                                           \
    __builtin_amdgcn_s_setprio(1);                                            \
    _Pragma("unroll") for (int fi = 0; fi < 4; fi++)                          \
      _Pragma("unroll") for (int fj = 0; fj < 2; fj++)                        \
        _Pragma("unroll") for (int kk = 0; kk < 2; kk++)                      \
          acc[(MQ) * 4 + fi][(NQ) * 2 + fj] =                                 \
              __builtin_amdgcn_mfma_f32_16x16x32_f16(                         \
                  ASET[fi * 2 + kk], BSET[fj * 2 + kk],                       \
                  acc[(MQ) * 4 + fi][(NQ) * 2 + fj], 0, 0, 0);                \
    __builtin_amdgcn_s_setprio(0);                                            \
  }
#define PHASE_WAIT()                                                          \
  __builtin_amdgcn_s_barrier();                                               \
  asm volatile("s_waitcnt lgkmcnt(0)" ::: "memory");                          \
  __builtin_amdgcn_sched_barrier(0);

// ---------------- 256x256 exp-logits GEMM, m201 quadrant-phase schedule ----
// (R12 core, verbatim — grid 256 = exactly 1 blk/CU, zero tail)
// C0[z*sC + n*ldc + m] = exp((A·B)[m][n]/32) f16x4, rowsum atomics.
__global__ __launch_bounds__(512) void gemm256_logits(
    const _Float16* __restrict__ A0, long long sA,
    const _Float16* __restrict__ B0, long long sB,
    void* __restrict__ C0, long long sC,
    float* __restrict__ rowsum, const int K, const int ldc) {
  __shared__ __align__(16) _Float16 As[2][2][8192];  // [buf][kk][256r x 32k]
  __shared__ __align__(16) _Float16 Bs[2][2][8192];
  const int tid = threadIdx.x;
  const int bid = blockIdx.x;

  const int w = (bid & 7) * 32 + (bid >> 3);   // [0,256), XCD chunk 32
  const int z = w >> 6;
  const int r0 = w & 63;
  const int bm0 = (r0 >> 3) * 256, bn0 = (r0 & 7) * 256;

  const _Float16* A = A0 + (size_t)z * sA;
  const _Float16* Bt = B0 + (size_t)z * sB;

  const _Float16* aS = A + (size_t)(bm0 + (tid >> 2)) * K + (tid & 3) * 8;
  const _Float16* bS = Bt + (size_t)(bn0 + (tid >> 2)) * K + (tid & 3) * 8;
  const size_t halfStep = (size_t)128 * K;

  auto stageA = [&](int X, int h) {
    const int b = X & 1;
    const _Float16* s = aS + (size_t)X * 64 + (size_t)h * halfStep;
    _Float16* d = &As[b][0][h * 4096 + tid * 8];
    __builtin_amdgcn_global_load_lds(AS1(s), AS3(d), 16, 0, 0);
    __builtin_amdgcn_global_load_lds(AS1(s + 32), AS3(d + 8192), 16, 0, 0);
  };
  auto stageB = [&](int X, int h) {
    const int b = X & 1;
    const _Float16* s = bS + (size_t)X * 64 + (size_t)h * halfStep;
    _Float16* d = &Bs[b][0][h * 4096 + tid * 8];
    __builtin_amdgcn_global_load_lds(AS1(s), AS3(d), 16, 0, 0);
    __builtin_amdgcn_global_load_lds(AS1(s + 32), AS3(d + 8192), 16, 0, 0);
  };

  const int lane = tid & 63, wave = tid >> 6;
  const int wr = wave >> 2, wc = wave & 3;
  const int quad = lane >> 4, l16 = lane & 15;

  f32x4 acc[8][4];
#pragma unroll
  for (int i = 0; i < 8; i++)
#pragma unroll
    for (int j = 0; j < 4; j++) {
      f32x4 zz = {0.f, 0.f, 0.f, 0.f};
      acc[i][j] = zz;
    }

  const int nt = K >> 6;

  stageA(0, 0); stageA(0, 1); stageB(0, 0); stageB(0, 1);
  stageA(1, 0); stageA(1, 1);
  asm volatile("s_waitcnt vmcnt(4)" ::: "memory");
  __builtin_amdgcn_s_barrier();

  f16x8 a0[8], a1[8], b0f[4], b1f[4];

  for (int T = 0; T < nt; ++T) {
    const int bb = T & 1;
    RD_A(a0, 0);
    RD_B(b0f, 0);
    if (T + 1 < nt) stageB(T + 1, 0);
    PHASE_WAIT();
    MFMA16(a0, b0f, 0, 0);
    __builtin_amdgcn_s_barrier();
    RD_A(a1, 1);
    if (T + 1 < nt) stageB(T + 1, 1);
    PHASE_WAIT();
    MFMA16(a1, b0f, 1, 0);
    __builtin_amdgcn_s_barrier();
    RD_B(b1f, 1);
    if (T + 2 < nt) stageA(T + 2, 0);
    PHASE_WAIT();
    MFMA16(a0, b1f, 0, 1);
    __builtin_amdgcn_s_barrier();
    if (T + 2 < nt) stageA(T + 2, 1);
    PHASE_WAIT();
    MFMA16(a1, b1f, 1, 1);
    if (T + 1 < nt) {
      if (T + 2 < nt) asm volatile("s_waitcnt vmcnt(4)" ::: "memory");
      else            asm volatile("s_waitcnt vmcnt(0)" ::: "memory");
      __builtin_amdgcn_s_barrier();
    }
  }

  const int rowb = bm0 + wr * 128 + quad * 4;
  const int colb = bn0 + wc * 64 + l16;
  _Float16* C = (_Float16*)C0 + (size_t)z * sC;
  float rs[4] = {0.f, 0.f, 0.f, 0.f};
#pragma unroll
  for (int i = 0; i < 8; i++)
#pragma unroll
    for (int j = 0; j < 4; j++) {
      const int gn = colb + j * 16;
      f16x4 o;
      float pj = 0.f;
#pragma unroll
      for (int r = 0; r < 4; r++) {
        const float e = __expf(acc[i][j][r] * 0.03125f);
        o[r] = (_Float16)e;
        pj += e;
      }
      rs[j] += pj;
      *(f16x4*)&C[(size_t)gn * ldc + rowb + i * 16] = o;
    }
#pragma unroll
  for (int j = 0; j < 4; j++) {
    float v = rs[j];
    v += __shfl_xor(v, 16);
    v += __shfl_xor(v, 32);
    if (quad == 0) atomicAdd(&rowsum[z * 2048 + colb + j * 16], v);
  }
}

// ---------------------------------------------------------------------------
extern "C" void kernel_launch(void* const* d_in, const int* in_sizes, int n_in,
                              void* d_out, int out_size, void* d_ws, size_t ws_size,
                              hipStream_t stream) {
  (void)in_sizes; (void)n_in; (void)out_size; (void)ws_size;
  const float* x  = (const float*)d_in[0];
  const float* Wq = (const float*)d_in[1];
  const float* bq = (const float*)d_in[2];
  const float* Wk = (const float*)d_in[3];
  const float* bk = (const float*)d_in[4];
  const float* Wv = (const float*)d_in[5];
  const float* bv = (const float*)d_in[6];
  float* out = (float*)d_out;
  char* ws = (char*)d_ws;

  // workspace layout (bytes):
  //   [0, 16M)        h (f16)          -- dead after QKV
  //   [16M, 22M)      Wt (f16 x3)      -- dead after QKV
  //   [22M, 70M)      qkv: q, k row-major; third slot holds vT[b][d][s]
  //   [70M, 102M)     attn_unnorm = exp(logits) (f16)
  //   [102M, +32K)    rowsum (fp32[8192]), zeroed by prep
  _Float16* h    = (_Float16*)(ws);
  _Float16* Wt   = (_Float16*)(ws + 16777216);
  _Float16* qkv  = (_Float16*)(ws + 23068672);
  _Float16* attn = (_Float16*)(ws + 73400320);
  float* rowsum  = (float*)   (ws + 106954752);

  const long long E = 8388608;  // elements per [8192 x 1024] f16 tensor
  _Float16* vT = qkv + 2 * E;   // [4][1024][2048], written directly by MODE 0

  // prep: [0,8192) make h; [8192,11264) transpose W; [11264,11296) zero rowsum
  prep<<<11296, 256, 0, stream>>>(x, h, Wq, Wk, Wv, Wt, rowsum);

  // QKV: [8192x1024] @ Wt_z -> q,k row-major f16 + bias; v written as vT
  gemm_bt<0><<<1536, 256, 0, stream>>>(
      h, 0LL, Wt, 1048576LL, qkv, E, bq, bk, bv, nullptr, vT,
      0LL, 1024, 1024, 0);

  // exp-logits^T (A=k, Bt=q -> attn[b][q][k] = exp(l/32), rowsum atomics)
  gemm256_logits<<<256, 512, 0, stream>>>(
      qkv + E, 2097152LL, qkv, 2097152LL, attn, 4194304LL,
      rowsum, 1024, 2048);

  // PV^T: A=vT_b, Bt=attn_b -> out[b][s][d] = (P~V)[s][d]/rowsum[s] + x
  gemm_bt<2><<<512, 256, 0, stream>>>(
      vT, 2097152LL, attn, 4194304LL, out, 2097152LL,
      x, nullptr, nullptr, rowsum, nullptr,
      2097152LL, 2048, 2048, 1024);
}